// Round 1
// baseline (118.792 us; speedup 1.0000x reference)
//
#include <hip/hip_runtime.h>
#include <math.h>

#define BROWS 512
#define SLEN  8192
#define NT    1024             // threads per block (16 waves)
#define CHUNK (SLEN / NT)      // 8 positions per thread
#define NWRD  (SLEN / 32)      // 256 mask words per row
#define MWRD  (NWRD + 2)       // +1 guard word each side

typedef float f32x4v __attribute__((ext_vector_type(4)));

// distance (capped; >5 -> 99) to nearest set bit within +/-5 of position t
__device__ __forceinline__ int win_dist(const unsigned int* __restrict__ M, int t) {
    int sI = t + 27;                   // (t-5) + 32-bit guard offset
    int w  = sI >> 5;
    int off = sI & 31;
    unsigned long long val =
        ((unsigned long long)M[w] | ((unsigned long long)M[w + 1] << 32)) >> off;
    unsigned int win = (unsigned int)val & 0x7FFu;   // bit5 == position t
    if (win & 32u) return 0;
    unsigned int dn = win & 31u;          // bits 0..4 = t-5..t-1 (bit i -> dist 5-i)
    unsigned int up = (win >> 6) & 31u;   // bits 0..4 = t+1..t+5 (bit j -> dist j+1)
    int d = 99;
    if (dn) d = 5 - (31 - __clz((int)dn));
    if (up) { int du = __ffs((int)up); if (du < d) d = du; }
    return d;
}

__device__ __forceinline__ float decay_pow(int d) {
    return (d == 1) ? 0.7f : (d == 2) ? 0.49f : (d == 3) ? 0.343f
         : (d == 4) ? 0.2401f : 0.16807f;
}

__global__ __launch_bounds__(NT, 8) void row_loss_kernel(
    const float* __restrict__ logits, const int* __restrict__ labels,
    double* __restrict__ psum, unsigned int* __restrict__ pcnt)
{
    __shared__ float         s_ce[SLEN];        // 32 KB (b128 reads in phase 3)
    __shared__ unsigned char s_pk[SLEN];        // 8 KB   pred(2b)|lab(2b)|valid(1b)
    __shared__ unsigned int  s_m[4][MWRD];      // ~4.1 KB  masks: t2, p2, t3, p3
    __shared__ unsigned int  s_wave[16];
    __shared__ unsigned int  s_wfl[16];
    __shared__ double        s_red[16];
    __shared__ int           s_redc[16];

    const int row  = blockIdx.x;
    const int tid  = threadIdx.x;
    const int lane = tid & 63;
    const int wid  = tid >> 6;
    const int half = lane >> 5;                 // which 32-lane half of the wave

    // only guard words need zeroing (interior fully written in phase 1 ballots)
    if (tid < 8) s_m[tid >> 1][(tid & 1) ? (MWRD - 1) : 0] = 0u;

    const f32x4v* lgv = (const f32x4v*)(logits + (size_t)row * SLEN * 4);
    const int*    lb  = labels + (size_t)row * SLEN;

    // ---- Phase 1: batched coalesced NT loads, argmax + weighted CE -> LDS,
    //      masks built in-place via wave ballots (strided layout is wave-aligned)
    int cnt = 0;
    unsigned int wfl = 0u;
    #pragma unroll
    for (int kk = 0; kk < CHUNK; kk += 4) {
        f32x4v v[4]; int la[4];
        #pragma unroll
        for (int j = 0; j < 4; ++j) {
            int t = (kk + j) * NT + tid;
            v[j]  = __builtin_nontemporal_load(lgv + t);
            la[j] = __builtin_nontemporal_load(lb + t);
        }
        #pragma unroll
        for (int j = 0; j < 4; ++j) {
            int t = (kk + j) * NT + tid;
            f32x4v q = v[j];
            int lab  = la[j];
            float m01 = fmaxf(q[0], q[1]), m23 = fmaxf(q[2], q[3]);
            float best = fmaxf(m01, m23);
            int pred = (best == q[0]) ? 0 : (best == q[1]) ? 1 : (best == q[2]) ? 2 : 3;
            bool valid = (lab != -100);
            cnt += valid ? 1 : 0;
            int l = valid ? (lab & 3) : 0;
            float se = __expf(q[0] - best) + __expf(q[1] - best) +
                       __expf(q[2] - best) + __expf(q[3] - best);
            float lse = best + __logf(se);
            float xl = (l == 0) ? q[0] : (l == 1) ? q[1] : (l == 2) ? q[2] : q[3];
            float wc = (l >= 2) ? 30.0f : 1.0f;
            s_ce[t] = valid ? (lse - xl) * wc : 0.0f;
            s_pk[t] = (unsigned char)(pred | (l << 2) | (valid ? 16 : 0));

            // position t = kk4*1024 + wid*64 + lane  ->  mask word = t>>5, bit = lane&31
            unsigned long long bt2 = __ballot(valid && l == 2);
            unsigned long long bp2 = __ballot(pred == 2);
            unsigned long long bt3 = __ballot(valid && l == 3);
            unsigned long long bp3 = __ballot(pred == 3);
            wfl |= (bt2 ? 1u : 0u) | (bp2 ? 2u : 0u) |
                   (bt3 ? 4u : 0u) | (bp3 ? 8u : 0u);
            if ((lane & 31) == 0) {
                int wi = 1 + (kk + j) * 32 + (wid << 1) + half;
                unsigned int sh = (unsigned int)(half << 5);
                s_m[0][wi] = (unsigned int)(bt2 >> sh);
                s_m[1][wi] = (unsigned int)(bp2 >> sh);
                s_m[2][wi] = (unsigned int)(bt3 >> sh);
                s_m[3][wi] = (unsigned int)(bp3 >> sh);
            }
        }
    }
    if (lane == 0) s_wfl[wid] = wfl;            // per-wave has-any flags (uniform)
    __syncthreads();   // A

    // ---- Phase 2: chunk summary + intra-wave fill-forward scan ----
    const int base = tid * CHUNK;
    const unsigned long long pkw = *(const unsigned long long*)(s_pk + base);
    unsigned int summary = 0;   // bit0 pm, bit1 tm, bit2 any_valid
    #pragma unroll
    for (int i = 0; i < CHUNK; ++i) {
        unsigned int pk = (unsigned int)(pkw >> (8 * i)) & 31u;
        if (pk & 16u) summary = 4u | (pk & 1u) | ((pk >> 1) & 2u);
    }
    unsigned int inc = summary;
    #pragma unroll
    for (int st = 1; st < 64; st <<= 1) {
        unsigned int o = __shfl_up(inc, st);
        if (lane >= st && !(inc & 4u)) inc = o;
    }
    unsigned int exc = __shfl_up(inc, 1);
    if (lane == 0) exc = 0u;
    if (lane == 63) s_wave[wid] = inc;
    __syncthreads();   // B

    // per-thread inter-wave fill-forward prefix (uniform broadcast LDS reads;
    // replaces the wave0 scan + extra barrier of the previous version)
    unsigned int wpre = 0u;
    for (int k = 0; k < wid; ++k) {
        unsigned int w = s_wave[k];
        if (w & 4u) wpre = w;
    }
    unsigned int flags = 0u;
    #pragma unroll
    for (int k = 0; k < 16; ++k) flags |= s_wfl[k];

    unsigned int pre = (exc & 4u) ? exc : wpre;
    int pm = (int)(pre & 1u), tm = (int)((pre >> 1) & 1u);
    const bool hasT2 = flags & 1u, hasP2 = flags & 2u;
    const bool hasT3 = flags & 4u, hasP3 = flags & 8u;

    // ---- Phase 3: replay with carry; merged window lookups; b128 ce reads ----
    f32x4v c0 = *(const f32x4v*)(s_ce + base);
    f32x4v c1 = *(const f32x4v*)(s_ce + base + 4);
    float cearr[8] = {c0[0], c0[1], c0[2], c0[3], c1[0], c1[1], c1[2], c1[3]};

    float acc = 0.0f;
    #pragma unroll
    for (int i = 0; i < CHUNK; ++i) {
        int t = base + i;
        unsigned int pk = (unsigned int)(pkw >> (8 * i)) & 31u;
        int pred = pk & 3, l = (pk >> 2) & 3;
        bool valid = (pk & 16) != 0;
        float m = 1.0f;
        if (valid) {
            bool bad = (pred == 2 && pm == 0) || (pred == 3 && pm == 1);
            if (bad) m *= 100.0f;
            bool good = (l == 2 && tm == 1 && pred == 2) ||
                        (l == 3 && tm == 0 && pred == 3);
            if (good) m *= 0.1f;
            pm = pred & 1;
            tm = l & 1;
        }
        if (pred >= 2) {                       // predicted-switch multiplier
            bool has = (pred == 2) ? hasT2 : hasT3;
            if (!has) m *= 20.0f;
            else {
                int d = win_dist(s_m[(pred - 2) << 1], t);
                m *= (d == 0) ? 0.1f : (d <= 5) ? decay_pow(d) : 10.0f;
            }
        }
        if (valid && l >= 2) {                 // true-switch multiplier
            bool has = (l == 2) ? hasP2 : hasP3;
            if (!has) m *= 3.0f;
            else if (win_dist(s_m[1 + ((l - 2) << 1)], t) > 5) m *= 2.0f;
        }
        acc += cearr[i] * m;
    }

    // ---- Reduce to per-row partial ----
    double dacc = (double)acc;
    #pragma unroll
    for (int o = 32; o > 0; o >>= 1) {
        dacc += __shfl_down(dacc, o);
        cnt  += __shfl_down(cnt, o);
    }
    if (lane == 0) { s_red[wid] = dacc; s_redc[wid] = cnt; }
    __syncthreads();   // D
    if (tid == 0) {
        double tot = 0.0; unsigned int c = 0;
        #pragma unroll
        for (int i = 0; i < 16; ++i) { tot += s_red[i]; c += (unsigned int)s_redc[i]; }
        psum[row] = tot;
        pcnt[row] = c;
    }
}

__global__ __launch_bounds__(512) void finalize_kernel(
    const double* __restrict__ psum, const unsigned int* __restrict__ pcnt,
    float* __restrict__ out)
{
    __shared__ double       sd[8];
    __shared__ unsigned int sc[8];
    int tid = threadIdx.x, lane = tid & 63, wid = tid >> 6;
    double v = psum[tid];
    unsigned int c = pcnt[tid];
    #pragma unroll
    for (int o = 32; o > 0; o >>= 1) {
        v += __shfl_down(v, o);
        c += __shfl_down(c, o);
    }
    if (lane == 0) { sd[wid] = v; sc[wid] = c; }
    __syncthreads();
    if (tid == 0) {
        double t = 0.0; unsigned int cc = 0;
        #pragma unroll
        for (int i = 0; i < 8; ++i) { t += sd[i]; cc += sc[i]; }
        double d = (cc > 0u) ? (double)cc : 1.0;
        out[0] = (float)(t / d);
    }
}

extern "C" void kernel_launch(void* const* d_in, const int* in_sizes, int n_in,
                              void* d_out, int out_size, void* d_ws, size_t ws_size,
                              hipStream_t stream) {
    const float* logits = (const float*)d_in[0];
    const int*   labels = (const int*)d_in[1];
    float* out = (float*)d_out;
    double* psum = (double*)d_ws;
    unsigned int* pcnt = (unsigned int*)(psum + BROWS);

    row_loss_kernel<<<BROWS, NT, 0, stream>>>(logits, labels, psum, pcnt);
    finalize_kernel<<<1, 512, 0, stream>>>(psum, pcnt, out);
}

// Round 2
// 113.071 us; speedup vs baseline: 1.0506x; 1.0506x over previous
//
#include <hip/hip_runtime.h>
#include <math.h>

#define BROWS 512
#define SLEN  8192
#define NT    1024             // threads per block (16 waves)
#define CHUNK (SLEN / NT)      // 8 positions per thread
#define NWRD  (SLEN / 32)      // 256 mask words per row
#define MWRD  (NWRD + 2)       // +1 guard word each side

// distance (capped; >5 -> 99) to nearest set bit within +/-5 of position t
__device__ __forceinline__ int win_dist(const unsigned int* __restrict__ M, int t) {
    int sI = t + 27;                   // (t-5) + 32-bit guard offset
    int w  = sI >> 5;
    int off = sI & 31;
    unsigned long long val =
        ((unsigned long long)M[w] | ((unsigned long long)M[w + 1] << 32)) >> off;
    unsigned int win = (unsigned int)val & 0x7FFu;   // bit5 == position t
    if (win & 32u) return 0;
    unsigned int dn = win & 31u;          // bits 0..4 = t-5..t-1 (bit i -> dist 5-i)
    unsigned int up = (win >> 6) & 31u;   // bits 0..4 = t+1..t+5 (bit j -> dist j+1)
    int d = 99;
    if (dn) d = 5 - (31 - __clz((int)dn));
    if (up) { int du = __ffs((int)up); if (du < d) d = du; }
    return d;
}

__device__ __forceinline__ float decay_pow(int d) {
    return (d == 1) ? 0.7f : (d == 2) ? 0.49f : (d == 3) ? 0.343f
         : (d == 4) ? 0.2401f : 0.16807f;
}

__global__ __launch_bounds__(NT, 8) void row_loss_kernel(
    const float* __restrict__ logits, const int* __restrict__ labels,
    double* __restrict__ psum, unsigned int* __restrict__ pcnt)
{
    __shared__ float         s_ce[SLEN];        // 32 KB (b128 reads in phase 3)
    __shared__ unsigned char s_pk[SLEN];        // 8 KB   pred(2b)|lab(2b)|valid(1b)
    __shared__ unsigned int  s_m[4][MWRD];      // ~4.1 KB  masks: t2, p2, t3, p3
    __shared__ unsigned int  s_wave[16];
    __shared__ unsigned int  s_flags;
    __shared__ double        s_red[16];
    __shared__ int           s_redc[16];

    const int row  = blockIdx.x;
    const int tid  = threadIdx.x;
    const int lane = tid & 63;
    const int wid  = tid >> 6;

    // only guard words need zeroing (interior fully written in phase 2)
    if (tid < 8) s_m[tid >> 1][(tid & 1) ? (MWRD - 1) : 0] = 0u;
    if (tid == 0) s_flags = 0u;

    const float4* lg4 = (const float4*)(logits + (size_t)row * SLEN * 4);
    const int*    lb  = labels + (size_t)row * SLEN;

    // ---- Phase 1: batched coalesced loads, argmax + weighted CE -> LDS ----
    // (byte-identical to the verified 112.8us version: no extra instructions
    //  in the memory-bound phase -- it is BW-limited, not issue-limited)
    int cnt = 0;
    #pragma unroll
    for (int kk = 0; kk < CHUNK; kk += 4) {
        float4 v[4]; int la[4];
        #pragma unroll
        for (int j = 0; j < 4; ++j) {
            int t = (kk + j) * NT + tid;
            v[j]  = lg4[t];
            la[j] = lb[t];
        }
        #pragma unroll
        for (int j = 0; j < 4; ++j) {
            int t = (kk + j) * NT + tid;
            float4 q = v[j];
            int lab  = la[j];
            float m01 = fmaxf(q.x, q.y), m23 = fmaxf(q.z, q.w);
            float best = fmaxf(m01, m23);
            int pred = (best == q.x) ? 0 : (best == q.y) ? 1 : (best == q.z) ? 2 : 3;
            bool valid = (lab != -100);
            cnt += valid ? 1 : 0;
            int l = valid ? (lab & 3) : 0;
            float se = __expf(q.x - best) + __expf(q.y - best) +
                       __expf(q.z - best) + __expf(q.w - best);
            float lse = best + __logf(se);
            float xl = (l == 0) ? q.x : (l == 1) ? q.y : (l == 2) ? q.z : q.w;
            float wc = (l >= 2) ? 30.0f : 1.0f;
            s_ce[t] = valid ? (lse - xl) * wc : 0.0f;
            s_pk[t] = (unsigned char)(pred | (l << 2) | (valid ? 16 : 0));
        }
    }
    __syncthreads();   // A

    // ---- Phase 2: per-chunk masks + mode-scan summary (one b64 pk read) ----
    const int base = tid * CHUNK;
    const unsigned long long pkw = *(const unsigned long long*)(s_pk + base);
    unsigned int mt2 = 0, mp2 = 0, mt3 = 0, mp3 = 0;
    unsigned int summary = 0;   // bit0 pm, bit1 tm, bit2 any_valid
    #pragma unroll
    for (int i = 0; i < CHUNK; ++i) {
        unsigned int pk = (unsigned int)(pkw >> (8 * i)) & 31u;
        int pred = pk & 3, l = (pk >> 2) & 3;
        bool valid = (pk & 16) != 0;
        if (pred == 2) mp2 |= 1u << i;
        if (pred == 3) mp3 |= 1u << i;
        if (valid && l == 2) mt2 |= 1u << i;
        if (valid && l == 3) mt3 |= 1u << i;
        if (valid) summary = 4u | (unsigned)(pred & 1) | ((unsigned)(l & 1) << 1);
    }
    {   // combine 4 lanes' bytes -> one word, single-lane plain write
        int sh = (tid & 3) * 8;
        unsigned int w0 = mt2 << sh, w1 = mp2 << sh, w2 = mt3 << sh, w3 = mp3 << sh;
        w0 |= __shfl_xor(w0, 1); w0 |= __shfl_xor(w0, 2);
        w1 |= __shfl_xor(w1, 1); w1 |= __shfl_xor(w1, 2);
        w2 |= __shfl_xor(w2, 1); w2 |= __shfl_xor(w2, 2);
        w3 |= __shfl_xor(w3, 1); w3 |= __shfl_xor(w3, 2);
        if ((tid & 3) == 0) {
            int wi = 1 + (tid >> 2);
            s_m[0][wi] = w0; s_m[1][wi] = w1; s_m[2][wi] = w2; s_m[3][wi] = w3;
        }
    }
    {   // row-wide has-any flags: wave OR-reduce, one LDS atomic per wave
        unsigned int fl = (mt2 ? 1u : 0u) | (mp2 ? 2u : 0u) |
                          (mt3 ? 4u : 0u) | (mp3 ? 8u : 0u);
        #pragma unroll
        for (int s = 32; s > 0; s >>= 1) fl |= __shfl_xor(fl, s);
        if (lane == 0 && fl) atomicOr(&s_flags, fl);
    }

    // ---- fill-forward scan over chunk summaries ----
    unsigned int inc = summary;
    #pragma unroll
    for (int st = 1; st < 64; st <<= 1) {
        unsigned int o = __shfl_up(inc, st);
        if (lane >= st && !(inc & 4u)) inc = o;
    }
    unsigned int exc = __shfl_up(inc, 1);
    if (lane == 0) exc = 0u;
    if (lane == 63) s_wave[wid] = inc;
    __syncthreads();   // B

    // inter-wave fill-forward prefix: per-thread loop over earlier waves'
    // summaries (<=15 uniform broadcast LDS reads, conflict-free). Replaces
    // the wave-0 serial scan + barrier C of the 112.8us version: one fewer
    // full-block barrier on the critical path.
    unsigned int wpre = 0u;
    for (int k = 0; k < wid; ++k) {
        unsigned int w = s_wave[k];
        if (w & 4u) wpre = w;
    }

    unsigned int pre = (exc & 4u) ? exc : wpre;
    int pm = (int)(pre & 1u), tm = (int)((pre >> 1) & 1u);
    const unsigned int flags = s_flags;
    const bool hasT2 = flags & 1u, hasP2 = flags & 2u;
    const bool hasT3 = flags & 4u, hasP3 = flags & 8u;

    // ---- Phase 3: replay with carry; merged window lookups; b128 ce reads ----
    float4 c0 = *(const float4*)(s_ce + base);
    float4 c1 = *(const float4*)(s_ce + base + 4);
    float cearr[8] = {c0.x, c0.y, c0.z, c0.w, c1.x, c1.y, c1.z, c1.w};

    float acc = 0.0f;
    #pragma unroll
    for (int i = 0; i < CHUNK; ++i) {
        int t = base + i;
        unsigned int pk = (unsigned int)(pkw >> (8 * i)) & 31u;
        int pred = pk & 3, l = (pk >> 2) & 3;
        bool valid = (pk & 16) != 0;
        float m = 1.0f;
        if (valid) {
            bool bad = (pred == 2 && pm == 0) || (pred == 3 && pm == 1);
            if (bad) m *= 100.0f;
            bool good = (l == 2 && tm == 1 && pred == 2) ||
                        (l == 3 && tm == 0 && pred == 3);
            if (good) m *= 0.1f;
            pm = pred & 1;
            tm = l & 1;
        }
        if (pred >= 2) {                       // predicted-switch multiplier
            bool has = (pred == 2) ? hasT2 : hasT3;
            if (!has) m *= 20.0f;
            else {
                int d = win_dist(s_m[(pred - 2) << 1], t);
                m *= (d == 0) ? 0.1f : (d <= 5) ? decay_pow(d) : 10.0f;
            }
        }
        if (valid && l >= 2) {                 // true-switch multiplier
            bool has = (l == 2) ? hasP2 : hasP3;
            if (!has) m *= 3.0f;
            else if (win_dist(s_m[1 + ((l - 2) << 1)], t) > 5) m *= 2.0f;
        }
        acc += cearr[i] * m;
    }

    // ---- Reduce to per-row partial ----
    double dacc = (double)acc;
    #pragma unroll
    for (int o = 32; o > 0; o >>= 1) {
        dacc += __shfl_down(dacc, o);
        cnt  += __shfl_down(cnt, o);
    }
    if (lane == 0) { s_red[wid] = dacc; s_redc[wid] = cnt; }
    __syncthreads();   // D
    if (tid == 0) {
        double tot = 0.0; unsigned int c = 0;
        #pragma unroll
        for (int i = 0; i < 16; ++i) { tot += s_red[i]; c += (unsigned int)s_redc[i]; }
        psum[row] = tot;
        pcnt[row] = c;
    }
}

__global__ __launch_bounds__(512) void finalize_kernel(
    const double* __restrict__ psum, const unsigned int* __restrict__ pcnt,
    float* __restrict__ out)
{
    __shared__ double       sd[8];
    __shared__ unsigned int sc[8];
    int tid = threadIdx.x, lane = tid & 63, wid = tid >> 6;
    double v = psum[tid];
    unsigned int c = pcnt[tid];
    #pragma unroll
    for (int o = 32; o > 0; o >>= 1) {
        v += __shfl_down(v, o);
        c += __shfl_down(c, o);
    }
    if (lane == 0) { sd[wid] = v; sc[wid] = c; }
    __syncthreads();
    if (tid == 0) {
        double t = 0.0; unsigned int cc = 0;
        #pragma unroll
        for (int i = 0; i < 8; ++i) { t += sd[i]; cc += sc[i]; }
        double d = (cc > 0u) ? (double)cc : 1.0;
        out[0] = (float)(t / d);
    }
}

extern "C" void kernel_launch(void* const* d_in, const int* in_sizes, int n_in,
                              void* d_out, int out_size, void* d_ws, size_t ws_size,
                              hipStream_t stream) {
    const float* logits = (const float*)d_in[0];
    const int*   labels = (const int*)d_in[1];
    float* out = (float*)d_out;
    double* psum = (double*)d_ws;
    unsigned int* pcnt = (unsigned int*)(psum + BROWS);

    row_loss_kernel<<<BROWS, NT, 0, stream>>>(logits, labels, psum, pcnt);
    finalize_kernel<<<1, 512, 0, stream>>>(psum, pcnt, out);
}